// Round 16
// baseline (322.689 us; speedup 1.0000x reference)
//
#include <hip/hip_runtime.h>
#include <stdint.h>

#define EMB 768
#define NBATCH 8
#define SEQ 2048
#define M_TOT (NBATCH*SEQ)   // 16384

using bf16x8 = __attribute__((ext_vector_type(8))) short;
using f32x4  = __attribute__((ext_vector_type(4))) float;

__device__ __forceinline__ short f2bf(float f) {
  __bf16 h = (__bf16)f;
  return __builtin_bit_cast(short, h);
}
__device__ __forceinline__ f32x4 MFMA(bf16x8 a, bf16x8 b, f32x4 c) {
  return __builtin_amdgcn_mfma_f32_16x16x32_bf16(a, b, c, 0, 0, 0);
}
#define GLOAD_LDS16(g, l) __builtin_amdgcn_global_load_lds( \
    (const __attribute__((address_space(1))) unsigned int*)(g), \
    (__attribute__((address_space(3))) unsigned int*)(l), 16, 0, 0)

__device__ __forceinline__ unsigned spread4(unsigned x) {
  x = (x | (x << 12)) & 0x000F000Fu;
  x = (x | (x << 6))  & 0x03030303u;
  x = (x | (x << 3))  & 0x11111111u;
  return x;
}

// ---------------------------------------------------------------------------
// cvt_xw: x, Wq|Wk|Wv fp32 -> bf16 (R10 form).
// ---------------------------------------------------------------------------
__global__ __launch_bounds__(256) void cvt_xw(
    const float* __restrict__ x, const float* __restrict__ Wq,
    const float* __restrict__ Wk, const float* __restrict__ Wv,
    short* __restrict__ xb, short* __restrict__ Wb)
{
  const size_t NXU = (size_t)M_TOT * EMB / 8;
  const size_t NWU = (size_t)EMB * EMB / 8;
  const size_t total = NXU + 3 * NWU;
  for (size_t u = (size_t)blockIdx.x * 256 + threadIdx.x; u < total;
       u += (size_t)gridDim.x * 256) {
    const float* src; short* dst; size_t off;
    if (u < NXU)            { src = x;  dst = xb;                     off = u; }
    else if (u < NXU+NWU)   { src = Wq; dst = Wb;                     off = u - NXU; }
    else if (u < NXU+2*NWU) { src = Wk; dst = Wb + (size_t)EMB*EMB;   off = u - NXU - NWU; }
    else                    { src = Wv; dst = Wb + (size_t)2*EMB*EMB; off = u - NXU - 2*NWU; }
    float4 a = reinterpret_cast<const float4*>(src)[off*2];
    float4 c = reinterpret_cast<const float4*>(src)[off*2+1];
    bf16x8 o;
    o[0]=f2bf(a.x); o[1]=f2bf(a.y); o[2]=f2bf(a.z); o[3]=f2bf(a.w);
    o[4]=f2bf(c.x); o[5]=f2bf(c.y); o[6]=f2bf(c.z); o[7]=f2bf(c.w);
    reinterpret_cast<bf16x8*>(dst)[off] = o;
  }
}

// ---------------------------------------------------------------------------
// m97-style 128x128 single-buffer 2-barrier machinery for qkv (R3-proven).
// ---------------------------------------------------------------------------
#define STAGE_128(As, Bs, asrc, bsrc, lda, ldb)                              \
  {                                                                          \
    _Pragma("unroll")                                                        \
    for (int i = 0; i < 4; ++i) {                                            \
      int slot = i*256 + t;                                                  \
      int row = slot >> 3, g = slot & 7;                                     \
      int gs = (g ^ (row & 7)) << 3;                                         \
      GLOAD_LDS16((asrc) + (size_t)row*(lda) + gs,                           \
                  (char*)&As[0] + (size_t)(i*256 + w*64)*16);                \
      GLOAD_LDS16((bsrc) + (size_t)row*(ldb) + gs,                           \
                  (char*)&Bs[0] + (size_t)(i*256 + w*64)*16);                \
    }                                                                        \
  }

#define MFMA_128(As, Bs)                                                     \
  {                                                                          \
    _Pragma("unroll")                                                        \
    for (int ks = 0; ks < 2; ++ks) {                                         \
      bf16x8 a[4], bb[4];                                                    \
      _Pragma("unroll")                                                      \
      for (int i = 0; i < 4; ++i) {                                          \
        int ra = wm*64 + i*16 + l15;                                         \
        a[i]  = *reinterpret_cast<const bf16x8*>(                            \
                  &As[ra*64 + (((ks*4 + l4) ^ (ra & 7)) << 3)]);             \
        int rb = wn*64 + i*16 + l15;                                         \
        bb[i] = *reinterpret_cast<const bf16x8*>(                            \
                  &Bs[rb*64 + (((ks*4 + l4) ^ (rb & 7)) << 3)]);             \
      }                                                                      \
      _Pragma("unroll")                                                      \
      for (int mi = 0; mi < 4; ++mi)                                         \
        _Pragma("unroll")                                                    \
        for (int ni = 0; ni < 4; ++ni)                                       \
          acc[mi][ni] = MFMA(a[mi], bb[ni], acc[mi][ni]);                    \
    }                                                                        \
  }

// ---------------------------------------------------------------------------
// qkv (R16: INTERLEAVED mask pack): C[m,f] = sum_e xb[m,e]*Wb[f,e].
// 128x128, grid 2304, 4 blocks/CU. Q/K row-major; V transposed.
// R14's pack ran as an aligned serial tail (~40us for a 20us stream); R15's
// full-row register prefetch SPILLED (32 VGPR live across the K-loop ->
// +150MB scratch traffic). R16 holds only ONE int4 chunk per row at a time:
// K-loop iter kk packs row-1 chunk kk (kk<8) and row-2 chunk kk-4 (kk>=4);
// each chunk's load issues one iteration ahead and is retired by the loop's
// existing vmcnt(0) -- no added waits, ~24 extra VGPR, loads ride the idle
// HBM under the GEMM. Ballot sequence == R12-verified pack (same grp==i
// select, same spread4 bijection: bit m of word ln <-> key 32*ln+m).
// All ballot guards are wave-uniform.
// ---------------------------------------------------------------------------
__global__ __launch_bounds__(256, 4) void qkv_gemm(
    const short* __restrict__ xb, const short* __restrict__ Wb,
    const int* __restrict__ mask,
    short* __restrict__ Qb, short* __restrict__ Kb, short* __restrict__ Vt,
    unsigned int* __restrict__ bits)
{
  __shared__ short As[128*64];
  __shared__ short Bs[128*64];

  const int bid = blockIdx.x;
  const int nb = (bid & 7) * 288 + (bid >> 3);     // XCD swizzle, 2304%8==0
  const int g = nb / 12, r = nb % 12;              // 4bm x 3bn supertiles
  const int bm = (g / 6) * 4 + r / 3;
  const int bn = (g % 6) * 3 + r % 3;
  const int mbase = bm * 128;

  const short* asrc = xb + (size_t)mbase * EMB;
  const short* bsrc = Wb + (size_t)bn * 128 * EMB;

  const int t = threadIdx.x, lane = t & 63, w = t >> 6;
  const int wm = w >> 1, wn = w & 1, l15 = lane & 15, l4 = lane >> 4;

  // mask rows owned by this wave
  const int gw = bid * 4 + w;                      // 0..9215
  const int row2 = gw + 9216;
  const bool has2 = (row2 < M_TOT);                // wave-uniform
  const int4* r1 = reinterpret_cast<const int4*>(mask + (size_t)gw * SEQ);
  const int4* r2 = reinterpret_cast<const int4*>(mask + (size_t)row2 * SEQ);
  const int grp = lane >> 3;
  unsigned long long s10=0, s11=0, s12=0, s13=0;   // row-1 selected ballots
  unsigned long long s20=0, s21=0, s22=0, s23=0;   // row-2 selected ballots
  int4 v1, v2;
  v1 = r1[lane];                                   // row-1 chunk 0

  f32x4 acc[4][4] = {};

  STAGE_128(As, Bs, asrc, bsrc, EMB, EMB);
  for (int kk = 0; kk < 12; ++kk) {
    asm volatile("s_waitcnt vmcnt(0)" ::: "memory");
    __syncthreads();
    MFMA_128(As, Bs);

    // ---- interleaved mask pack (one chunk per row per iteration) ----
    if (kk < 8) {                                  // pack row-1 chunk kk
      unsigned long long b0 = __ballot(v1.x != 0);
      unsigned long long b1 = __ballot(v1.y != 0);
      unsigned long long b2 = __ballot(v1.z != 0);
      unsigned long long b3 = __ballot(v1.w != 0);
      if (grp == kk) { s10 = b0; s11 = b1; s12 = b2; s13 = b3; }
      if (kk < 7) v1 = r1[(kk+1)*64 + lane];       // next chunk, 1 iter ahead
    }
    if (kk >= 4 && has2) {                         // pack row-2 chunk kk-4
      unsigned long long b0 = __ballot(v2.x != 0);
      unsigned long long b1 = __ballot(v2.y != 0);
      unsigned long long b2 = __ballot(v2.z != 0);
      unsigned long long b3 = __ballot(v2.w != 0);
      if (grp == kk-4) { s20 = b0; s21 = b1; s22 = b2; s23 = b3; }
    }
    if (kk >= 3 && kk < 11 && has2)
      v2 = r2[(kk-3)*64 + lane];                   // row-2 chunk kk-3

    if (kk < 11) {
      __syncthreads();
      STAGE_128(As, Bs, asrc + (kk+1)*64, bsrc + (kk+1)*64, EMB, EMB);
    }
  }

#pragma unroll
  for (int mi = 0; mi < 4; ++mi) {
#pragma unroll
    for (int ni = 0; ni < 4; ++ni) {
      int f = bn * 128 + wn * 64 + ni * 16 + l15;
      int m0 = mbase + wm * 64 + mi * 16 + l4 * 4;
      f32x4 v = acc[mi][ni];
      if (f < 1536) {
        short* dst = (f < 768) ? (Qb + f) : (Kb + (f - 768));
#pragma unroll
        for (int j = 0; j < 4; ++j)
          dst[(size_t)(m0 + j) * EMB] = f2bf(v[j]);
      } else {
        int f2 = f - 1536, bb2 = m0 >> 11, s = m0 & 2047;
        short4 pk = make_short4(f2bf(v[0]), f2bf(v[1]), f2bf(v[2]), f2bf(v[3]));
        *reinterpret_cast<short4*>(&Vt[((size_t)bb2 * EMB + f2) * SEQ + s]) = pk;
      }
    }
  }

  // ---- assemble + store bitmask words (pure ALU tail) ----
  {
    const int sh = (lane & 7) * 8;
    unsigned w1 = spread4((unsigned)(s10 >> sh) & 0xffu)
                | (spread4((unsigned)(s11 >> sh) & 0xffu) << 1)
                | (spread4((unsigned)(s12 >> sh) & 0xffu) << 2)
                | (spread4((unsigned)(s13 >> sh) & 0xffu) << 3);
    bits[(size_t)gw * 64 + lane] = w1;
    if (has2) {
      unsigned w2 = spread4((unsigned)(s20 >> sh) & 0xffu)
                  | (spread4((unsigned)(s21 >> sh) & 0xffu) << 1)
                  | (spread4((unsigned)(s22 >> sh) & 0xffu) << 2)
                  | (spread4((unsigned)(s23 >> sh) & 0xffu) << 3);
      bits[(size_t)row2 * 64 + lane] = w2;
    }
  }
}

// ---------------------------------------------------------------------------
// 8-phase 256x256 GEMM machinery (R10 4-wait schedule, verified):
// fragment caching (24 ds_read_b128/K-tile), vmcnt(4) counted waits,
// drain-first vmcnt(0) epilogue, raw s_barrier, setprio around MFMA.
// ---------------------------------------------------------------------------
#define STAGE_HALF(ldsb, src, ld, k0, h)                                      \
  { _Pragma("unroll") for (int i_ = 0; i_ < 2; ++i_) {                        \
      int slot_ = i_*512 + t;                                                 \
      int row_ = (h)*128 + (slot_ >> 3), g_ = slot_ & 7;                      \
      GLOAD_LDS16((src) + (size_t)row_*(ld) + (k0) + ((g_ ^ (row_ & 7)) << 3),\
                  (ldsb) + (h)*16384 + (size_t)(i_*512 + w*64)*16); } }

#define READ_A(mh)                                                            \
  _Pragma("unroll") for (int ks_ = 0; ks_ < 2; ++ks_)                         \
    _Pragma("unroll") for (int mi_ = 0; mi_ < 4; ++mi_) {                     \
      int r_ = (mh)*128 + wm*64 + mi_*16 + l15;                               \
      a_c[ks_][mi_] = *reinterpret_cast<const bf16x8*>(                       \
          Ar + r_*64 + (((ks_*4 + l4) ^ (r_ & 7)) << 3));                     \
    }

#define READ_B(nh)                                                            \
  _Pragma("unroll") for (int ks_ = 0; ks_ < 2; ++ks_)                         \
    _Pragma("unroll") for (int ni_ = 0; ni_ < 2; ++ni_) {                     \
      int r_ = (nh)*128 + wn*32 + ni_*16 + l15;                               \
      b_c[nh][ks_][ni_] = *reinterpret_cast<const bf16x8*>(                   \
          Br + r_*64 + (((ks_*4 + l4) ^ (r_ & 7)) << 3));                     \
    }

#define PHASE(mh, nh, W, RD, ...)                                             \
  {                                                                           \
    RD                                                                        \
    __VA_ARGS__                                                               \
    asm volatile("s_waitcnt vmcnt(" #W ")" ::: "memory");                     \
    asm volatile("s_barrier" ::: "memory");                                   \
    __builtin_amdgcn_s_setprio(1);                                            \
    _Pragma("unroll") for (int ks_ = 0; ks_ < 2; ++ks_)                       \
      _Pragma("unroll") for (int mi_ = 0; mi_ < 4; ++mi_)                     \
        _Pragma("unroll") for (int ni_ = 0; ni_ < 2; ++ni_)                   \
          acc[mh][nh][mi_][ni_] =                                             \
              MFMA(a_c[ks_][mi_], b_c[nh][ks_][ni_], acc[mh][nh][mi_][ni_]);  \
    __builtin_amdgcn_s_setprio(0);                                            \
    asm volatile("s_barrier" ::: "memory");                                   \
  }

#define GEMM_PRO_BODY(asrc, bsrc, lda, ldb, NT)                               \
  short* const A0p = (short*)smem;                                            \
  short* const B0p = (short*)(smem + 32768);                                  \
  short* const A1p = (short*)(smem + 65536);                                  \
  short* const B1p = (short*)(smem + 98304);                                  \
  f32x4 acc[2][2][4][2] = {};                                                 \
  bf16x8 a_c[2][4], b_c[2][2][2];                                             \
  STAGE_HALF((char*)A0p, asrc, lda, 0, 0);                                    \
  STAGE_HALF((char*)B0p, bsrc, ldb, 0, 0);                                    \
  STAGE_HALF((char*)B0p, bsrc, ldb, 0, 1);                                    \
  STAGE_HALF((char*)A0p, asrc, lda, 0, 1);                                    \
  asm volatile("s_waitcnt vmcnt(4)" ::: "memory");                            \
  asm volatile("s_barrier" ::: "memory");                                     \
  for (int T = 0; T < (NT) - 1; ++T) {                                        \
    short* Ar = (T & 1) ? A1p : A0p;                                          \
    short* Br = (T & 1) ? B1p : B0p;                                          \
    char* Aw = (char*)((T & 1) ? A0p : A1p);                                  \
    char* Bw = (char*)((T & 1) ? B0p : B1p);                                  \
    const int nk = (T + 1) * 64;                                              \
    PHASE(0,0, 4, READ_A(0) READ_B(0), STAGE_HALF(Aw, asrc, lda, nk, 0))      \
    PHASE(0,1, 4, READ_B(1),           STAGE_HALF(Bw, bsrc, ldb, nk, 0))      \
    PHASE(1,0, 4, READ_A(1),           STAGE_HALF(Bw, bsrc, ldb, nk, 1))      \
    PHASE(1,1, 4, ,                    STAGE_HALF(Aw, asrc, lda, nk, 1))      \
  }                                                                           \
  {                                                                           \
    short* Ar = (((NT)-1) & 1) ? A1p : A0p;                                   \
    short* Br = (((NT)-1) & 1) ? B1p : B0p;                                   \
    asm volatile("s_waitcnt vmcnt(0)" ::: "memory");  /* drain-first */       \
    asm volatile("s_barrier" ::: "memory");                                   \
    PHASE(0,0, 0, READ_A(0) READ_B(0), )                                      \
    PHASE(0,1, 0, READ_B(1), )                                                \
    PHASE(1,0, 0, READ_A(1), )                                                \
    PHASE(1,1, 0, , )                                                         \
  }

// ---------------------------------------------------------------------------
// energy (R12-verified bitmask epilogue): P = bit ? exp2(Q.K*SCL) : 0,
// unnormalized (softmax shift-invariance); bf16 P + deterministic per-block
// row sums. Bitmask words broadcast across the 16 l15-lanes (L1/L2 hit).
// ---------------------------------------------------------------------------
__global__ __launch_bounds__(512, 2) void energy(
    const short* __restrict__ Qb, const short* __restrict__ Kb,
    const unsigned int* __restrict__ bitw, short* __restrict__ S,
    float* __restrict__ partial)
{
  extern __shared__ char smem[];
  const int t = threadIdx.x, lane = t & 63, w = t >> 6;
  const int wm = w >> 2, wn = w & 3, l15 = lane & 15, l4 = lane >> 4;

  const int bid = blockIdx.x;
  const int nb = (bid & 7) * 64 + (bid >> 3);      // 512 % 8 == 0
  const int b = nb >> 6;                           // batch per XCD
  const int idx = nb & 63;
  const int sup = idx >> 2, sub = idx & 3;         // 2x2 supertiles
  const int qt = (sup >> 2) * 2 + (sub >> 1);
  const int kt = (sup & 3) * 2 + (sub & 1);

  const short* asrc = Qb + ((size_t)b*SEQ + qt*256) * EMB;
  const short* bsrc = Kb + ((size_t)b*SEQ + kt*256) * EMB;

  GEMM_PRO_BODY(asrc, bsrc, EMB, EMB, 12)

  const float SCL = 1.4426950408889634f / 27.712812921102035f;  // log2e/sqrt(768)
  short* srow = S + (size_t)b * SEQ * SEQ;

  float rsum[2][4][4];
#pragma unroll
  for (int mh = 0; mh < 2; ++mh)
#pragma unroll
    for (int mi = 0; mi < 4; ++mi)
#pragma unroll
      for (int j = 0; j < 4; ++j) rsum[mh][mi][j] = 0.f;

#pragma unroll
  for (int mh = 0; mh < 2; ++mh)
#pragma unroll
  for (int mi = 0; mi < 4; ++mi)
#pragma unroll
  for (int j = 0; j < 4; ++j) {
    int q = qt*256 + mh*128 + wm*64 + mi*16 + l4*4 + j;
    size_t qg = (size_t)b*SEQ + q;                 // global row
#pragma unroll
    for (int nh = 0; nh < 2; ++nh) {
      unsigned int wrd = bitw[qg*64 + kt*8 + nh*4 + wn];  // broadcast per 16 lanes
#pragma unroll
      for (int ni = 0; ni < 2; ++ni) {
        float p = ((wrd >> (ni*16 + l15)) & 1u)
                    ? __builtin_amdgcn_exp2f(acc[mh][nh][mi][ni][j] * SCL) : 0.f;
        srow[(size_t)q*SEQ + kt*256 + nh*128 + wn*32 + ni*16 + l15] = f2bf(p);
        rsum[mh][mi][j] += p;
      }
    }
  }
  // reduce this wave's k-slice partial over l15 (lane bits 0-3 only)
#pragma unroll
  for (int off = 8; off >= 1; off >>= 1)
#pragma unroll
    for (int mh = 0; mh < 2; ++mh)
#pragma unroll
      for (int mi = 0; mi < 4; ++mi)
#pragma unroll
        for (int j = 0; j < 4; ++j)
          rsum[mh][mi][j] += __shfl_xor(rsum[mh][mi][j], off);

  float* sm = (float*)smem;                        // [4 wn][256 rows]
  if (l15 == 0) {
#pragma unroll
    for (int mh = 0; mh < 2; ++mh)
#pragma unroll
      for (int mi = 0; mi < 4; ++mi)
#pragma unroll
        for (int j = 0; j < 4; ++j)
          sm[wn*256 + mh*128 + wm*64 + mi*16 + l4*4 + j] = rsum[mh][mi][j];
  }
  __syncthreads();
  if (t < 256) {
    float s4 = (sm[t] + sm[256+t]) + (sm[512+t] + sm[768+t]);  // fixed order
    partial[(size_t)kt*M_TOT + b*SEQ + qt*256 + t] = s4;
  }
}

// ---------------------------------------------------------------------------
// lred: invl[row] = 1 / sum_kt partial[kt][row]. Deterministic. Grid 64.
// ---------------------------------------------------------------------------
__global__ __launch_bounds__(256) void lred(
    const float* __restrict__ partial, float* __restrict__ invl)
{
  int i = blockIdx.x * 256 + threadIdx.x;
  float s = 0.f;
#pragma unroll
  for (int kt = 0; kt < 8; ++kt) s += partial[(size_t)kt*M_TOT + i];
  invl[i] = 1.0f / s;
}

// ---------------------------------------------------------------------------
// pv: out[b,q,d] = invl[b,q] * sum_k P[b,q,k]*Vt[b,d,k]. Grid 192 =
// 8 b x 8 qt x 3 dt (batch per XCD). K-tiles 32.
// ---------------------------------------------------------------------------
__global__ __launch_bounds__(512, 2) void pv(
    const short* __restrict__ P, const short* __restrict__ Vt,
    const float* __restrict__ invl, float* __restrict__ out)
{
  extern __shared__ char smem[];
  const int t = threadIdx.x, lane = t & 63, w = t >> 6;
  const int wm = w >> 2, wn = w & 3, l15 = lane & 15, l4 = lane >> 4;

  const int bid = blockIdx.x;
  const int nb = (bid & 7) * 24 + (bid >> 3);      // 192 % 8 == 0
  const int b = nb / 24;
  const int idx = nb % 24;
  const int qt = idx / 3, dt = idx % 3;

  const short* asrc = P  + ((size_t)b*SEQ + qt*256) * SEQ;
  const short* bsrc = Vt + ((size_t)b*EMB + dt*256) * SEQ;

  GEMM_PRO_BODY(asrc, bsrc, SEQ, SEQ, 32)

#pragma unroll
  for (int mh = 0; mh < 2; ++mh)
#pragma unroll
  for (int nh = 0; nh < 2; ++nh)
#pragma unroll
  for (int mi = 0; mi < 4; ++mi)
#pragma unroll
  for (int j = 0; j < 4; ++j) {
    int q = qt*256 + mh*128 + wm*64 + mi*16 + l4*4 + j;
    float il = invl[b*SEQ + q];
    float* orow = out + ((size_t)b*SEQ + q) * EMB;
#pragma unroll
    for (int ni = 0; ni < 2; ++ni) {
      int d = dt*256 + nh*128 + wn*32 + ni*16 + l15;
      orow[d] = acc[mh][nh][mi][ni][j] * il;
    }
  }
}

// ---------------------------------------------------------------------------
extern "C" void kernel_launch(void* const* d_in, const int* in_sizes, int n_in,
                              void* d_out, int out_size, void* d_ws, size_t ws_size,
                              hipStream_t stream)
{
  (void)in_sizes; (void)n_in; (void)out_size; (void)ws_size;
  const float* x  = (const float*)d_in[0];
  const float* Wv = (const float*)d_in[1];
  const float* Wk = (const float*)d_in[2];
  const float* Wq = (const float*)d_in[3];
  const int* mask = (const int*)d_in[4];
  float* out = (float*)d_out;

  // ws: Qb | Kb | Vt (bf16, 24MiB each) | S/P (bf16, 64MiB) | partial | invl
  // (~136.6 MiB). xb/Wb alias S (dead before energy writes P). Bitmask
  // (4 MiB) lives in d_out -- written by qkv's interleaved packer, consumed
  // by energy, overwritten by pv.
  short* Qb = (short*)d_ws;
  short* Kb = Qb + (size_t)M_TOT * EMB;
  short* Vt = Kb + (size_t)M_TOT * EMB;
  short* S  = Vt + (size_t)M_TOT * EMB;
  float* partial = (float*)(S + (size_t)NBATCH * SEQ * SEQ);   // 8*M_TOT f32
  float* invl = partial + (size_t)8 * M_TOT;                   // M_TOT f32
  short* xb = S;
  short* Wb = S + (size_t)M_TOT * EMB;
  unsigned int* bits = (unsigned int*)d_out;                   // 4 MiB scratch

  cvt_xw<<<dim3(2048), dim3(256), 0, stream>>>(x, Wq, Wk, Wv, xb, Wb);
  qkv_gemm<<<dim3(2304), dim3(256), 0, stream>>>(xb, Wb, mask, Qb, Kb, Vt, bits);
  energy<<<dim3(512), dim3(512), 131072, stream>>>(Qb, Kb, bits, S, partial);
  lred<<<dim3(64), dim3(256), 0, stream>>>(partial, invl);
  pv<<<dim3(192), dim3(512), 131072, stream>>>(S, Vt, invl, out);
}

// Round 17
// 229.683 us; speedup vs baseline: 1.4049x; 1.4049x over previous
//
#include <hip/hip_runtime.h>
#include <stdint.h>

#define EMB 768
#define NBATCH 8
#define SEQ 2048
#define M_TOT (NBATCH*SEQ)   // 16384

using bf16x8 = __attribute__((ext_vector_type(8))) short;
using f32x4  = __attribute__((ext_vector_type(4))) float;

__device__ __forceinline__ short f2bf(float f) {
  __bf16 h = (__bf16)f;
  return __builtin_bit_cast(short, h);
}
__device__ __forceinline__ f32x4 MFMA(bf16x8 a, bf16x8 b, f32x4 c) {
  return __builtin_amdgcn_mfma_f32_16x16x32_bf16(a, b, c, 0, 0, 0);
}
#define GLOAD_LDS16(g, l) __builtin_amdgcn_global_load_lds( \
    (const __attribute__((address_space(1))) unsigned int*)(g), \
    (__attribute__((address_space(3))) unsigned int*)(l), 16, 0, 0)

__device__ __forceinline__ unsigned spread4(unsigned x) {
  x = (x | (x << 12)) & 0x000F000Fu;
  x = (x | (x << 6))  & 0x03030303u;
  x = (x | (x << 3))  & 0x11111111u;
  return x;
}

// ---------------------------------------------------------------------------
// cvt_xw: x, Wq|Wk|Wv fp32 -> bf16 (R10 form).
// ---------------------------------------------------------------------------
__global__ __launch_bounds__(256) void cvt_xw(
    const float* __restrict__ x, const float* __restrict__ Wq,
    const float* __restrict__ Wk, const float* __restrict__ Wv,
    short* __restrict__ xb, short* __restrict__ Wb)
{
  const size_t NXU = (size_t)M_TOT * EMB / 8;
  const size_t NWU = (size_t)EMB * EMB / 8;
  const size_t total = NXU + 3 * NWU;
  for (size_t u = (size_t)blockIdx.x * 256 + threadIdx.x; u < total;
       u += (size_t)gridDim.x * 256) {
    const float* src; short* dst; size_t off;
    if (u < NXU)            { src = x;  dst = xb;                     off = u; }
    else if (u < NXU+NWU)   { src = Wq; dst = Wb;                     off = u - NXU; }
    else if (u < NXU+2*NWU) { src = Wk; dst = Wb + (size_t)EMB*EMB;   off = u - NXU - NWU; }
    else                    { src = Wv; dst = Wb + (size_t)2*EMB*EMB; off = u - NXU - 2*NWU; }
    float4 a = reinterpret_cast<const float4*>(src)[off*2];
    float4 c = reinterpret_cast<const float4*>(src)[off*2+1];
    bf16x8 o;
    o[0]=f2bf(a.x); o[1]=f2bf(a.y); o[2]=f2bf(a.z); o[3]=f2bf(a.w);
    o[4]=f2bf(c.x); o[5]=f2bf(c.y); o[6]=f2bf(c.z); o[7]=f2bf(c.w);
    reinterpret_cast<bf16x8*>(dst)[off] = o;
  }
}

// ---------------------------------------------------------------------------
// m97-style 128x128 single-buffer 2-barrier machinery for qkv (R3-proven).
// ---------------------------------------------------------------------------
#define STAGE_128(As, Bs, asrc, bsrc, lda, ldb)                              \
  {                                                                          \
    _Pragma("unroll")                                                        \
    for (int i = 0; i < 4; ++i) {                                            \
      int slot = i*256 + t;                                                  \
      int row = slot >> 3, g = slot & 7;                                     \
      int gs = (g ^ (row & 7)) << 3;                                         \
      GLOAD_LDS16((asrc) + (size_t)row*(lda) + gs,                           \
                  (char*)&As[0] + (size_t)(i*256 + w*64)*16);                \
      GLOAD_LDS16((bsrc) + (size_t)row*(ldb) + gs,                           \
                  (char*)&Bs[0] + (size_t)(i*256 + w*64)*16);                \
    }                                                                        \
  }

#define MFMA_128(As, Bs)                                                     \
  {                                                                          \
    _Pragma("unroll")                                                        \
    for (int ks = 0; ks < 2; ++ks) {                                         \
      bf16x8 a[4], bb[4];                                                    \
      _Pragma("unroll")                                                      \
      for (int i = 0; i < 4; ++i) {                                          \
        int ra = wm*64 + i*16 + l15;                                         \
        a[i]  = *reinterpret_cast<const bf16x8*>(                            \
                  &As[ra*64 + (((ks*4 + l4) ^ (ra & 7)) << 3)]);             \
        int rb = wn*64 + i*16 + l15;                                         \
        bb[i] = *reinterpret_cast<const bf16x8*>(                            \
                  &Bs[rb*64 + (((ks*4 + l4) ^ (rb & 7)) << 3)]);             \
      }                                                                      \
      _Pragma("unroll")                                                      \
      for (int mi = 0; mi < 4; ++mi)                                         \
        _Pragma("unroll")                                                    \
        for (int ni = 0; ni < 4; ++ni)                                       \
          acc[mi][ni] = MFMA(a[mi], bb[ni], acc[mi][ni]);                    \
    }                                                                        \
  }

// ---------------------------------------------------------------------------
// qkv (R14 form, measured best): C[m,f] = sum_e xb[m,e]*Wb[f,e].
// 128x128, grid 2304, 4 blocks/CU. Q/K row-major; V transposed.
// Fused mask pack as a wave-independent tail (R12-verified pattern):
// 8 int4 loads (1KB/instr), 4 ballots/load, spread4 bijection, lane ln
// writes word ln (bit m <-> key 32*ln+m). Measured ~40us for the 128MB
// stream -- empirical minimum across 6 variants (R13 LDS-staged serialized,
// R15 prefetch spilled, R16 interleave spilled).
// ---------------------------------------------------------------------------
__global__ __launch_bounds__(256, 4) void qkv_gemm(
    const short* __restrict__ xb, const short* __restrict__ Wb,
    const int* __restrict__ mask,
    short* __restrict__ Qb, short* __restrict__ Kb, short* __restrict__ Vt,
    unsigned int* __restrict__ bits)
{
  __shared__ short As[128*64];
  __shared__ short Bs[128*64];

  const int bid = blockIdx.x;
  const int nb = (bid & 7) * 288 + (bid >> 3);     // XCD swizzle, 2304%8==0
  const int g = nb / 12, r = nb % 12;              // 4bm x 3bn supertiles
  const int bm = (g / 6) * 4 + r / 3;
  const int bn = (g % 6) * 3 + r % 3;
  const int mbase = bm * 128;

  const short* asrc = xb + (size_t)mbase * EMB;
  const short* bsrc = Wb + (size_t)bn * 128 * EMB;

  const int t = threadIdx.x, lane = t & 63, w = t >> 6;
  const int wm = w >> 1, wn = w & 1, l15 = lane & 15, l4 = lane >> 4;

  f32x4 acc[4][4] = {};

  STAGE_128(As, Bs, asrc, bsrc, EMB, EMB);
  for (int kk = 0; kk < 12; ++kk) {
    asm volatile("s_waitcnt vmcnt(0)" ::: "memory");
    __syncthreads();
    MFMA_128(As, Bs);
    if (kk < 11) {
      __syncthreads();
      STAGE_128(As, Bs, asrc + (kk+1)*64, bsrc + (kk+1)*64, EMB, EMB);
    }
  }

#pragma unroll
  for (int mi = 0; mi < 4; ++mi) {
#pragma unroll
    for (int ni = 0; ni < 4; ++ni) {
      int f = bn * 128 + wn * 64 + ni * 16 + l15;
      int m0 = mbase + wm * 64 + mi * 16 + l4 * 4;
      f32x4 v = acc[mi][ni];
      if (f < 1536) {
        short* dst = (f < 768) ? (Qb + f) : (Kb + (f - 768));
#pragma unroll
        for (int j = 0; j < 4; ++j)
          dst[(size_t)(m0 + j) * EMB] = f2bf(v[j]);
      } else {
        int f2 = f - 1536, bb2 = m0 >> 11, s = m0 & 2047;
        short4 pk = make_short4(f2bf(v[0]), f2bf(v[1]), f2bf(v[2]), f2bf(v[3]));
        *reinterpret_cast<short4*>(&Vt[((size_t)bb2 * EMB + f2) * SEQ + s]) = pk;
      }
    }
  }

  // ---- fused mask pack (R12 pattern, wave-independent, no barrier) ----
  {
    const int gw = bid * 4 + w;                    // 9216 waves total
    for (int row = gw; row < M_TOT; row += 2304 * 4) {
      const int4* row4 = reinterpret_cast<const int4*>(mask + (size_t)row * SEQ);
      int4 v[8];
#pragma unroll
      for (int i = 0; i < 8; ++i) v[i] = row4[i*64 + lane];
      unsigned long long sel0 = 0, sel1 = 0, sel2 = 0, sel3 = 0;
      const int grp = lane >> 3;
#pragma unroll
      for (int i = 0; i < 8; ++i) {
        unsigned long long b0 = __ballot(v[i].x != 0);
        unsigned long long b1 = __ballot(v[i].y != 0);
        unsigned long long b2 = __ballot(v[i].z != 0);
        unsigned long long b3 = __ballot(v[i].w != 0);
        if (grp == i) { sel0 = b0; sel1 = b1; sel2 = b2; sel3 = b3; }
      }
      const int sh = (lane & 7) * 8;
      unsigned wrd = spread4((unsigned)(sel0 >> sh) & 0xffu)
                   | (spread4((unsigned)(sel1 >> sh) & 0xffu) << 1)
                   | (spread4((unsigned)(sel2 >> sh) & 0xffu) << 2)
                   | (spread4((unsigned)(sel3 >> sh) & 0xffu) << 3);
      bits[(size_t)row * 64 + lane] = wrd;
    }
  }
}

// ---------------------------------------------------------------------------
// 8-phase 256x256 GEMM machinery (R10 4-wait schedule, verified):
// fragment caching (24 ds_read_b128/K-tile), vmcnt(4) counted waits,
// drain-first vmcnt(0) epilogue, raw s_barrier, setprio around MFMA.
// ---------------------------------------------------------------------------
#define STAGE_HALF(ldsb, src, ld, k0, h)                                      \
  { _Pragma("unroll") for (int i_ = 0; i_ < 2; ++i_) {                        \
      int slot_ = i_*512 + t;                                                 \
      int row_ = (h)*128 + (slot_ >> 3), g_ = slot_ & 7;                      \
      GLOAD_LDS16((src) + (size_t)row_*(ld) + (k0) + ((g_ ^ (row_ & 7)) << 3),\
                  (ldsb) + (h)*16384 + (size_t)(i_*512 + w*64)*16); } }

#define READ_A(mh)                                                            \
  _Pragma("unroll") for (int ks_ = 0; ks_ < 2; ++ks_)                         \
    _Pragma("unroll") for (int mi_ = 0; mi_ < 4; ++mi_) {                     \
      int r_ = (mh)*128 + wm*64 + mi_*16 + l15;                               \
      a_c[ks_][mi_] = *reinterpret_cast<const bf16x8*>(                       \
          Ar + r_*64 + (((ks_*4 + l4) ^ (r_ & 7)) << 3));                     \
    }

#define READ_B(nh)                                                            \
  _Pragma("unroll") for (int ks_ = 0; ks_ < 2; ++ks_)                         \
    _Pragma("unroll") for (int ni_ = 0; ni_ < 2; ++ni_) {                     \
      int r_ = (nh)*128 + wn*32 + ni_*16 + l15;                               \
      b_c[nh][ks_][ni_] = *reinterpret_cast<const bf16x8*>(                   \
          Br + r_*64 + (((ks_*4 + l4) ^ (r_ & 7)) << 3));                     \
    }

#define PHASE(mh, nh, W, RD, ...)                                             \
  {                                                                           \
    RD                                                                        \
    __VA_ARGS__                                                               \
    asm volatile("s_waitcnt vmcnt(" #W ")" ::: "memory");                     \
    asm volatile("s_barrier" ::: "memory");                                   \
    __builtin_amdgcn_s_setprio(1);                                            \
    _Pragma("unroll") for (int ks_ = 0; ks_ < 2; ++ks_)                       \
      _Pragma("unroll") for (int mi_ = 0; mi_ < 4; ++mi_)                     \
        _Pragma("unroll") for (int ni_ = 0; ni_ < 2; ++ni_)                   \
          acc[mh][nh][mi_][ni_] =                                             \
              MFMA(a_c[ks_][mi_], b_c[nh][ks_][ni_], acc[mh][nh][mi_][ni_]);  \
    __builtin_amdgcn_s_setprio(0);                                            \
    asm volatile("s_barrier" ::: "memory");                                   \
  }

#define GEMM_PRO_BODY(asrc, bsrc, lda, ldb, NT)                               \
  short* const A0p = (short*)smem;                                            \
  short* const B0p = (short*)(smem + 32768);                                  \
  short* const A1p = (short*)(smem + 65536);                                  \
  short* const B1p = (short*)(smem + 98304);                                  \
  f32x4 acc[2][2][4][2] = {};                                                 \
  bf16x8 a_c[2][4], b_c[2][2][2];                                             \
  STAGE_HALF((char*)A0p, asrc, lda, 0, 0);                                    \
  STAGE_HALF((char*)B0p, bsrc, ldb, 0, 0);                                    \
  STAGE_HALF((char*)B0p, bsrc, ldb, 0, 1);                                    \
  STAGE_HALF((char*)A0p, asrc, lda, 0, 1);                                    \
  asm volatile("s_waitcnt vmcnt(4)" ::: "memory");                            \
  asm volatile("s_barrier" ::: "memory");                                     \
  for (int T = 0; T < (NT) - 1; ++T) {                                        \
    short* Ar = (T & 1) ? A1p : A0p;                                          \
    short* Br = (T & 1) ? B1p : B0p;                                          \
    char* Aw = (char*)((T & 1) ? A0p : A1p);                                  \
    char* Bw = (char*)((T & 1) ? B0p : B1p);                                  \
    const int nk = (T + 1) * 64;                                              \
    PHASE(0,0, 4, READ_A(0) READ_B(0), STAGE_HALF(Aw, asrc, lda, nk, 0))      \
    PHASE(0,1, 4, READ_B(1),           STAGE_HALF(Bw, bsrc, ldb, nk, 0))      \
    PHASE(1,0, 4, READ_A(1),           STAGE_HALF(Bw, bsrc, ldb, nk, 1))      \
    PHASE(1,1, 4, ,                    STAGE_HALF(Aw, asrc, lda, nk, 1))      \
  }                                                                           \
  {                                                                           \
    short* Ar = (((NT)-1) & 1) ? A1p : A0p;                                   \
    short* Br = (((NT)-1) & 1) ? B1p : B0p;                                   \
    asm volatile("s_waitcnt vmcnt(0)" ::: "memory");  /* drain-first */       \
    asm volatile("s_barrier" ::: "memory");                                   \
    PHASE(0,0, 0, READ_A(0) READ_B(0), )                                      \
    PHASE(0,1, 0, READ_B(1), )                                                \
    PHASE(1,0, 0, READ_A(1), )                                                \
    PHASE(1,1, 0, , )                                                         \
  }

// ---------------------------------------------------------------------------
// energy (R12-verified bitmask epilogue): P = bit ? exp2(Q.K*SCL) : 0,
// unnormalized (softmax shift-invariance); bf16 P + deterministic per-block
// row sums. Bitmask words broadcast across the 16 l15-lanes (L1/L2 hit).
// ---------------------------------------------------------------------------
__global__ __launch_bounds__(512, 2) void energy(
    const short* __restrict__ Qb, const short* __restrict__ Kb,
    const unsigned int* __restrict__ bitw, short* __restrict__ S,
    float* __restrict__ partial)
{
  extern __shared__ char smem[];
  const int t = threadIdx.x, lane = t & 63, w = t >> 6;
  const int wm = w >> 2, wn = w & 3, l15 = lane & 15, l4 = lane >> 4;

  const int bid = blockIdx.x;
  const int nb = (bid & 7) * 64 + (bid >> 3);      // 512 % 8 == 0
  const int b = nb >> 6;                           // batch per XCD
  const int idx = nb & 63;
  const int sup = idx >> 2, sub = idx & 3;         // 2x2 supertiles
  const int qt = (sup >> 2) * 2 + (sub >> 1);
  const int kt = (sup & 3) * 2 + (sub & 1);

  const short* asrc = Qb + ((size_t)b*SEQ + qt*256) * EMB;
  const short* bsrc = Kb + ((size_t)b*SEQ + kt*256) * EMB;

  GEMM_PRO_BODY(asrc, bsrc, EMB, EMB, 12)

  const float SCL = 1.4426950408889634f / 27.712812921102035f;  // log2e/sqrt(768)
  short* srow = S + (size_t)b * SEQ * SEQ;

  float rsum[2][4][4];
#pragma unroll
  for (int mh = 0; mh < 2; ++mh)
#pragma unroll
    for (int mi = 0; mi < 4; ++mi)
#pragma unroll
      for (int j = 0; j < 4; ++j) rsum[mh][mi][j] = 0.f;

#pragma unroll
  for (int mh = 0; mh < 2; ++mh)
#pragma unroll
  for (int mi = 0; mi < 4; ++mi)
#pragma unroll
  for (int j = 0; j < 4; ++j) {
    int q = qt*256 + mh*128 + wm*64 + mi*16 + l4*4 + j;
    size_t qg = (size_t)b*SEQ + q;                 // global row
#pragma unroll
    for (int nh = 0; nh < 2; ++nh) {
      unsigned int wrd = bitw[qg*64 + kt*8 + nh*4 + wn];  // broadcast per 16 lanes
#pragma unroll
      for (int ni = 0; ni < 2; ++ni) {
        float p = ((wrd >> (ni*16 + l15)) & 1u)
                    ? __builtin_amdgcn_exp2f(acc[mh][nh][mi][ni][j] * SCL) : 0.f;
        srow[(size_t)q*SEQ + kt*256 + nh*128 + wn*32 + ni*16 + l15] = f2bf(p);
        rsum[mh][mi][j] += p;
      }
    }
  }
  // reduce this wave's k-slice partial over l15 (lane bits 0-3 only)
#pragma unroll
  for (int off = 8; off >= 1; off >>= 1)
#pragma unroll
    for (int mh = 0; mh < 2; ++mh)
#pragma unroll
      for (int mi = 0; mi < 4; ++mi)
#pragma unroll
        for (int j = 0; j < 4; ++j)
          rsum[mh][mi][j] += __shfl_xor(rsum[mh][mi][j], off);

  float* sm = (float*)smem;                        // [4 wn][256 rows]
  if (l15 == 0) {
#pragma unroll
    for (int mh = 0; mh < 2; ++mh)
#pragma unroll
      for (int mi = 0; mi < 4; ++mi)
#pragma unroll
        for (int j = 0; j < 4; ++j)
          sm[wn*256 + mh*128 + wm*64 + mi*16 + l4*4 + j] = rsum[mh][mi][j];
  }
  __syncthreads();
  if (t < 256) {
    float s4 = (sm[t] + sm[256+t]) + (sm[512+t] + sm[768+t]);  // fixed order
    partial[(size_t)kt*M_TOT + b*SEQ + qt*256 + t] = s4;
  }
}

// ---------------------------------------------------------------------------
// lred: invl[row] = 1 / sum_kt partial[kt][row]. Deterministic. Grid 64.
// ---------------------------------------------------------------------------
__global__ __launch_bounds__(256) void lred(
    const float* __restrict__ partial, float* __restrict__ invl)
{
  int i = blockIdx.x * 256 + threadIdx.x;
  float s = 0.f;
#pragma unroll
  for (int kt = 0; kt < 8; ++kt) s += partial[(size_t)kt*M_TOT + i];
  invl[i] = 1.0f / s;
}

// ---------------------------------------------------------------------------
// pv: out[b,q,d] = invl[b,q] * sum_k P[b,q,k]*Vt[b,d,k]. Grid 192 =
// 8 b x 8 qt x 3 dt (batch per XCD). K-tiles 32.
// ---------------------------------------------------------------------------
__global__ __launch_bounds__(512, 2) void pv(
    const short* __restrict__ P, const short* __restrict__ Vt,
    const float* __restrict__ invl, float* __restrict__ out)
{
  extern __shared__ char smem[];
  const int t = threadIdx.x, lane = t & 63, w = t >> 6;
  const int wm = w >> 2, wn = w & 3, l15 = lane & 15, l4 = lane >> 4;

  const int bid = blockIdx.x;
  const int nb = (bid & 7) * 24 + (bid >> 3);      // 192 % 8 == 0
  const int b = nb / 24;
  const int idx = nb % 24;
  const int qt = idx / 3, dt = idx % 3;

  const short* asrc = P  + ((size_t)b*SEQ + qt*256) * SEQ;
  const short* bsrc = Vt + ((size_t)b*EMB + dt*256) * SEQ;

  GEMM_PRO_BODY(asrc, bsrc, SEQ, SEQ, 32)

#pragma unroll
  for (int mh = 0; mh < 2; ++mh)
#pragma unroll
  for (int nh = 0; nh < 2; ++nh)
#pragma unroll
  for (int mi = 0; mi < 4; ++mi)
#pragma unroll
  for (int j = 0; j < 4; ++j) {
    int q = qt*256 + mh*128 + wm*64 + mi*16 + l4*4 + j;
    float il = invl[b*SEQ + q];
    float* orow = out + ((size_t)b*SEQ + q) * EMB;
#pragma unroll
    for (int ni = 0; ni < 2; ++ni) {
      int d = dt*256 + nh*128 + wn*32 + ni*16 + l15;
      orow[d] = acc[mh][nh][mi][ni][j] * il;
    }
  }
}

// ---------------------------------------------------------------------------
extern "C" void kernel_launch(void* const* d_in, const int* in_sizes, int n_in,
                              void* d_out, int out_size, void* d_ws, size_t ws_size,
                              hipStream_t stream)
{
  (void)in_sizes; (void)n_in; (void)out_size; (void)ws_size;
  const float* x  = (const float*)d_in[0];
  const float* Wv = (const float*)d_in[1];
  const float* Wk = (const float*)d_in[2];
  const float* Wq = (const float*)d_in[3];
  const int* mask = (const int*)d_in[4];
  float* out = (float*)d_out;

  // ws: Qb | Kb | Vt (bf16, 24MiB each) | S/P (bf16, 64MiB) | partial | invl
  // (~136.6 MiB). xb/Wb alias S (dead before energy writes P). Bitmask
  // (4 MiB) lives in d_out -- written by qkv's fused packer, consumed by
  // energy, overwritten by pv.
  short* Qb = (short*)d_ws;
  short* Kb = Qb + (size_t)M_TOT * EMB;
  short* Vt = Kb + (size_t)M_TOT * EMB;
  short* S  = Vt + (size_t)M_TOT * EMB;
  float* partial = (float*)(S + (size_t)NBATCH * SEQ * SEQ);   // 8*M_TOT f32
  float* invl = partial + (size_t)8 * M_TOT;                   // M_TOT f32
  short* xb = S;
  short* Wb = S + (size_t)M_TOT * EMB;
  unsigned int* bits = (unsigned int*)d_out;                   // 4 MiB scratch

  cvt_xw<<<dim3(2048), dim3(256), 0, stream>>>(x, Wq, Wk, Wv, xb, Wb);
  qkv_gemm<<<dim3(2304), dim3(256), 0, stream>>>(xb, Wb, mask, Qb, Kb, Vt, bits);
  energy<<<dim3(512), dim3(512), 131072, stream>>>(Qb, Kb, bits, S, partial);
  lred<<<dim3(64), dim3(256), 0, stream>>>(partial, invl);
  pv<<<dim3(192), dim3(512), 131072, stream>>>(S, Vt, invl, out);
}

// Round 18
// 229.648 us; speedup vs baseline: 1.4051x; 1.0002x over previous
//
#include <hip/hip_runtime.h>
#include <stdint.h>

#define EMB 768
#define NBATCH 8
#define SEQ 2048
#define M_TOT (NBATCH*SEQ)   // 16384

using bf16x8 = __attribute__((ext_vector_type(8))) short;
using f32x4  = __attribute__((ext_vector_type(4))) float;

__device__ __forceinline__ short f2bf(float f) {
  __bf16 h = (__bf16)f;
  return __builtin_bit_cast(short, h);
}
__device__ __forceinline__ f32x4 MFMA(bf16x8 a, bf16x8 b, f32x4 c) {
  return __builtin_amdgcn_mfma_f32_16x16x32_bf16(a, b, c, 0, 0, 0);
}
#define GLOAD_LDS16(g, l) __builtin_amdgcn_global_load_lds( \
    (const __attribute__((address_space(1))) unsigned int*)(g), \
    (__attribute__((address_space(3))) unsigned int*)(l), 16, 0, 0)

__device__ __forceinline__ unsigned spread4(unsigned x) {
  x = (x | (x << 12)) & 0x000F000Fu;
  x = (x | (x << 6))  & 0x03030303u;
  x = (x | (x << 3))  & 0x11111111u;
  return x;
}

// ---------------------------------------------------------------------------
// cvt_xw: x, Wq|Wk|Wv fp32 -> bf16 (R10 form).
// ---------------------------------------------------------------------------
__global__ __launch_bounds__(256) void cvt_xw(
    const float* __restrict__ x, const float* __restrict__ Wq,
    const float* __restrict__ Wk, const float* __restrict__ Wv,
    short* __restrict__ xb, short* __restrict__ Wb)
{
  const size_t NXU = (size_t)M_TOT * EMB / 8;
  const size_t NWU = (size_t)EMB * EMB / 8;
  const size_t total = NXU + 3 * NWU;
  for (size_t u = (size_t)blockIdx.x * 256 + threadIdx.x; u < total;
       u += (size_t)gridDim.x * 256) {
    const float* src; short* dst; size_t off;
    if (u < NXU)            { src = x;  dst = xb;                     off = u; }
    else if (u < NXU+NWU)   { src = Wq; dst = Wb;                     off = u - NXU; }
    else if (u < NXU+2*NWU) { src = Wk; dst = Wb + (size_t)EMB*EMB;   off = u - NXU - NWU; }
    else                    { src = Wv; dst = Wb + (size_t)2*EMB*EMB; off = u - NXU - 2*NWU; }
    float4 a = reinterpret_cast<const float4*>(src)[off*2];
    float4 c = reinterpret_cast<const float4*>(src)[off*2+1];
    bf16x8 o;
    o[0]=f2bf(a.x); o[1]=f2bf(a.y); o[2]=f2bf(a.z); o[3]=f2bf(a.w);
    o[4]=f2bf(c.x); o[5]=f2bf(c.y); o[6]=f2bf(c.z); o[7]=f2bf(c.w);
    reinterpret_cast<bf16x8*>(dst)[off] = o;
  }
}

// ---------------------------------------------------------------------------
// m97-style 128x128 single-buffer 2-barrier machinery for qkv (R3-proven).
// ---------------------------------------------------------------------------
#define STAGE_128(As, Bs, asrc, bsrc, lda, ldb)                              \
  {                                                                          \
    _Pragma("unroll")                                                        \
    for (int i = 0; i < 4; ++i) {                                            \
      int slot = i*256 + t;                                                  \
      int row = slot >> 3, g = slot & 7;                                     \
      int gs = (g ^ (row & 7)) << 3;                                         \
      GLOAD_LDS16((asrc) + (size_t)row*(lda) + gs,                           \
                  (char*)&As[0] + (size_t)(i*256 + w*64)*16);                \
      GLOAD_LDS16((bsrc) + (size_t)row*(ldb) + gs,                           \
                  (char*)&Bs[0] + (size_t)(i*256 + w*64)*16);                \
    }                                                                        \
  }

#define MFMA_128(As, Bs)                                                     \
  {                                                                          \
    _Pragma("unroll")                                                        \
    for (int ks = 0; ks < 2; ++ks) {                                         \
      bf16x8 a[4], bb[4];                                                    \
      _Pragma("unroll")                                                      \
      for (int i = 0; i < 4; ++i) {                                          \
        int ra = wm*64 + i*16 + l15;                                         \
        a[i]  = *reinterpret_cast<const bf16x8*>(                            \
                  &As[ra*64 + (((ks*4 + l4) ^ (ra & 7)) << 3)]);             \
        int rb = wn*64 + i*16 + l15;                                         \
        bb[i] = *reinterpret_cast<const bf16x8*>(                            \
                  &Bs[rb*64 + (((ks*4 + l4) ^ (rb & 7)) << 3)]);             \
      }                                                                      \
      _Pragma("unroll")                                                      \
      for (int mi = 0; mi < 4; ++mi)                                         \
        _Pragma("unroll")                                                    \
        for (int ni = 0; ni < 4; ++ni)                                       \
          acc[mi][ni] = MFMA(a[mi], bb[ni], acc[mi][ni]);                    \
    }                                                                        \
  }

// ---------------------------------------------------------------------------
// qkv (R14 form, measured best): C[m,f] = sum_e xb[m,e]*Wb[f,e].
// 128x128, grid 2304, 4 blocks/CU. Q/K row-major; V transposed.
// Fused mask pack as a wave-independent tail (R12-verified pattern).
// ---------------------------------------------------------------------------
__global__ __launch_bounds__(256, 4) void qkv_gemm(
    const short* __restrict__ xb, const short* __restrict__ Wb,
    const int* __restrict__ mask,
    short* __restrict__ Qb, short* __restrict__ Kb, short* __restrict__ Vt,
    unsigned int* __restrict__ bits)
{
  __shared__ short As[128*64];
  __shared__ short Bs[128*64];

  const int bid = blockIdx.x;
  const int nb = (bid & 7) * 288 + (bid >> 3);     // XCD swizzle, 2304%8==0
  const int g = nb / 12, r = nb % 12;              // 4bm x 3bn supertiles
  const int bm = (g / 6) * 4 + r / 3;
  const int bn = (g % 6) * 3 + r % 3;
  const int mbase = bm * 128;

  const short* asrc = xb + (size_t)mbase * EMB;
  const short* bsrc = Wb + (size_t)bn * 128 * EMB;

  const int t = threadIdx.x, lane = t & 63, w = t >> 6;
  const int wm = w >> 1, wn = w & 1, l15 = lane & 15, l4 = lane >> 4;

  f32x4 acc[4][4] = {};

  STAGE_128(As, Bs, asrc, bsrc, EMB, EMB);
  for (int kk = 0; kk < 12; ++kk) {
    asm volatile("s_waitcnt vmcnt(0)" ::: "memory");
    __syncthreads();
    MFMA_128(As, Bs);
    if (kk < 11) {
      __syncthreads();
      STAGE_128(As, Bs, asrc + (kk+1)*64, bsrc + (kk+1)*64, EMB, EMB);
    }
  }

#pragma unroll
  for (int mi = 0; mi < 4; ++mi) {
#pragma unroll
    for (int ni = 0; ni < 4; ++ni) {
      int f = bn * 128 + wn * 64 + ni * 16 + l15;
      int m0 = mbase + wm * 64 + mi * 16 + l4 * 4;
      f32x4 v = acc[mi][ni];
      if (f < 1536) {
        short* dst = (f < 768) ? (Qb + f) : (Kb + (f - 768));
#pragma unroll
        for (int j = 0; j < 4; ++j)
          dst[(size_t)(m0 + j) * EMB] = f2bf(v[j]);
      } else {
        int f2 = f - 1536, bb2 = m0 >> 11, s = m0 & 2047;
        short4 pk = make_short4(f2bf(v[0]), f2bf(v[1]), f2bf(v[2]), f2bf(v[3]));
        *reinterpret_cast<short4*>(&Vt[((size_t)bb2 * EMB + f2) * SEQ + s]) = pk;
      }
    }
  }

  // ---- fused mask pack (R12 pattern, wave-independent, no barrier) ----
  {
    const int gw = bid * 4 + w;                    // 9216 waves total
    for (int row = gw; row < M_TOT; row += 2304 * 4) {
      const int4* row4 = reinterpret_cast<const int4*>(mask + (size_t)row * SEQ);
      int4 v[8];
#pragma unroll
      for (int i = 0; i < 8; ++i) v[i] = row4[i*64 + lane];
      unsigned long long sel0 = 0, sel1 = 0, sel2 = 0, sel3 = 0;
      const int grp = lane >> 3;
#pragma unroll
      for (int i = 0; i < 8; ++i) {
        unsigned long long b0 = __ballot(v[i].x != 0);
        unsigned long long b1 = __ballot(v[i].y != 0);
        unsigned long long b2 = __ballot(v[i].z != 0);
        unsigned long long b3 = __ballot(v[i].w != 0);
        if (grp == i) { sel0 = b0; sel1 = b1; sel2 = b2; sel3 = b3; }
      }
      const int sh = (lane & 7) * 8;
      unsigned wrd = spread4((unsigned)(sel0 >> sh) & 0xffu)
                   | (spread4((unsigned)(sel1 >> sh) & 0xffu) << 1)
                   | (spread4((unsigned)(sel2 >> sh) & 0xffu) << 2)
                   | (spread4((unsigned)(sel3 >> sh) & 0xffu) << 3);
      bits[(size_t)row * 64 + lane] = wrd;
    }
  }
}

// ---------------------------------------------------------------------------
// 8-phase 256x256 GEMM machinery, R18 = R11's 2-wait schedule (correctness-
// validated in R11; isolated here per the R11/R12 total decomposition which
// attributes ~14us of R11's GEMM-side gain to it).
// Ledger (per-wave FIFO, stage order a0,b0,b1,a1 @2 loads each):
//   phi1: reads A.h0,B.h0 (retired by prev phi4's vmcnt(4)+barrier);
//         issues a0'; vmcnt(2) retires prev b1,a1 -> protects phi2/phi3.
//   phi2: reads B.h1; issues b0'; NO wait.
//   phi3: reads A.h1; issues b1'; NO wait.
//   phi4: no reads; issues a1'; vmcnt(4) retires a0',b0' -> next phi1 safe.
// Prologue vmcnt(4); drain-first vmcnt(0) epilogue (R5 fix) unchanged.
// Fragment caching (24 ds_read_b128/K-tile), setprio around MFMA.
// ---------------------------------------------------------------------------
#define STAGE_HALF(ldsb, src, ld, k0, h)                                      \
  { _Pragma("unroll") for (int i_ = 0; i_ < 2; ++i_) {                        \
      int slot_ = i_*512 + t;                                                 \
      int row_ = (h)*128 + (slot_ >> 3), g_ = slot_ & 7;                      \
      GLOAD_LDS16((src) + (size_t)row_*(ld) + (k0) + ((g_ ^ (row_ & 7)) << 3),\
                  (ldsb) + (h)*16384 + (size_t)(i_*512 + w*64)*16); } }

#define VMW(N) asm volatile("s_waitcnt vmcnt(" #N ")" ::: "memory");

#define READ_A(mh)                                                            \
  _Pragma("unroll") for (int ks_ = 0; ks_ < 2; ++ks_)                         \
    _Pragma("unroll") for (int mi_ = 0; mi_ < 4; ++mi_) {                     \
      int r_ = (mh)*128 + wm*64 + mi_*16 + l15;                               \
      a_c[ks_][mi_] = *reinterpret_cast<const bf16x8*>(                       \
          Ar + r_*64 + (((ks_*4 + l4) ^ (r_ & 7)) << 3));                     \
    }

#define READ_B(nh)                                                            \
  _Pragma("unroll") for (int ks_ = 0; ks_ < 2; ++ks_)                         \
    _Pragma("unroll") for (int ni_ = 0; ni_ < 2; ++ni_) {                     \
      int r_ = (nh)*128 + wn*32 + ni_*16 + l15;                               \
      b_c[nh][ks_][ni_] = *reinterpret_cast<const bf16x8*>(                   \
          Br + r_*64 + (((ks_*4 + l4) ^ (r_ & 7)) << 3));                     \
    }

#define PHASE(mh, nh, WAIT, RD, ...)                                          \
  {                                                                           \
    RD                                                                        \
    __VA_ARGS__                                                               \
    WAIT                                                                      \
    asm volatile("s_barrier" ::: "memory");                                   \
    __builtin_amdgcn_s_setprio(1);                                            \
    _Pragma("unroll") for (int ks_ = 0; ks_ < 2; ++ks_)                       \
      _Pragma("unroll") for (int mi_ = 0; mi_ < 4; ++mi_)                     \
        _Pragma("unroll") for (int ni_ = 0; ni_ < 2; ++ni_)                   \
          acc[mh][nh][mi_][ni_] =                                             \
              MFMA(a_c[ks_][mi_], b_c[nh][ks_][ni_], acc[mh][nh][mi_][ni_]);  \
    __builtin_amdgcn_s_setprio(0);                                            \
    asm volatile("s_barrier" ::: "memory");                                   \
  }

#define GEMM_PRO_BODY(asrc, bsrc, lda, ldb, NT)                               \
  short* const A0p = (short*)smem;                                            \
  short* const B0p = (short*)(smem + 32768);                                  \
  short* const A1p = (short*)(smem + 65536);                                  \
  short* const B1p = (short*)(smem + 98304);                                  \
  f32x4 acc[2][2][4][2] = {};                                                 \
  bf16x8 a_c[2][4], b_c[2][2][2];                                             \
  STAGE_HALF((char*)A0p, asrc, lda, 0, 0);                                    \
  STAGE_HALF((char*)B0p, bsrc, ldb, 0, 0);                                    \
  STAGE_HALF((char*)B0p, bsrc, ldb, 0, 1);                                    \
  STAGE_HALF((char*)A0p, asrc, lda, 0, 1);                                    \
  asm volatile("s_waitcnt vmcnt(4)" ::: "memory");                            \
  asm volatile("s_barrier" ::: "memory");                                     \
  for (int T = 0; T < (NT) - 1; ++T) {                                        \
    short* Ar = (T & 1) ? A1p : A0p;                                          \
    short* Br = (T & 1) ? B1p : B0p;                                          \
    char* Aw = (char*)((T & 1) ? A0p : A1p);                                  \
    char* Bw = (char*)((T & 1) ? B0p : B1p);                                  \
    const int nk = (T + 1) * 64;                                              \
    PHASE(0,0, VMW(2), READ_A(0) READ_B(0), STAGE_HALF(Aw, asrc, lda, nk, 0)) \
    PHASE(0,1, ,       READ_B(1),           STAGE_HALF(Bw, bsrc, ldb, nk, 0)) \
    PHASE(1,0, ,       READ_A(1),           STAGE_HALF(Bw, bsrc, ldb, nk, 1)) \
    PHASE(1,1, VMW(4), ,                    STAGE_HALF(Aw, asrc, lda, nk, 1)) \
  }                                                                           \
  {                                                                           \
    short* Ar = (((NT)-1) & 1) ? A1p : A0p;                                   \
    short* Br = (((NT)-1) & 1) ? B1p : B0p;                                   \
    asm volatile("s_waitcnt vmcnt(0)" ::: "memory");  /* drain-first */       \
    asm volatile("s_barrier" ::: "memory");                                   \
    PHASE(0,0, , READ_A(0) READ_B(0), )                                       \
    PHASE(0,1, , READ_B(1), )                                                 \
    PHASE(1,0, , READ_A(1), )                                                 \
    PHASE(1,1, , , )                                                          \
  }

// ---------------------------------------------------------------------------
// energy (R12-verified bitmask epilogue): P = bit ? exp2(Q.K*SCL) : 0,
// unnormalized (softmax shift-invariance); bf16 P + deterministic per-block
// row sums. Bitmask words broadcast across the 16 l15-lanes (L1/L2 hit).
// ---------------------------------------------------------------------------
__global__ __launch_bounds__(512, 2) void energy(
    const short* __restrict__ Qb, const short* __restrict__ Kb,
    const unsigned int* __restrict__ bitw, short* __restrict__ S,
    float* __restrict__ partial)
{
  extern __shared__ char smem[];
  const int t = threadIdx.x, lane = t & 63, w = t >> 6;
  const int wm = w >> 2, wn = w & 3, l15 = lane & 15, l4 = lane >> 4;

  const int bid = blockIdx.x;
  const int nb = (bid & 7) * 64 + (bid >> 3);      // 512 % 8 == 0
  const int b = nb >> 6;                           // batch per XCD
  const int idx = nb & 63;
  const int sup = idx >> 2, sub = idx & 3;         // 2x2 supertiles
  const int qt = (sup >> 2) * 2 + (sub >> 1);
  const int kt = (sup & 3) * 2 + (sub & 1);

  const short* asrc = Qb + ((size_t)b*SEQ + qt*256) * EMB;
  const short* bsrc = Kb + ((size_t)b*SEQ + kt*256) * EMB;

  GEMM_PRO_BODY(asrc, bsrc, EMB, EMB, 12)

  const float SCL = 1.4426950408889634f / 27.712812921102035f;  // log2e/sqrt(768)
  short* srow = S + (size_t)b * SEQ * SEQ;

  float rsum[2][4][4];
#pragma unroll
  for (int mh = 0; mh < 2; ++mh)
#pragma unroll
    for (int mi = 0; mi < 4; ++mi)
#pragma unroll
      for (int j = 0; j < 4; ++j) rsum[mh][mi][j] = 0.f;

#pragma unroll
  for (int mh = 0; mh < 2; ++mh)
#pragma unroll
  for (int mi = 0; mi < 4; ++mi)
#pragma unroll
  for (int j = 0; j < 4; ++j) {
    int q = qt*256 + mh*128 + wm*64 + mi*16 + l4*4 + j;
    size_t qg = (size_t)b*SEQ + q;                 // global row
#pragma unroll
    for (int nh = 0; nh < 2; ++nh) {
      unsigned int wrd = bitw[qg*64 + kt*8 + nh*4 + wn];  // broadcast per 16 lanes
#pragma unroll
      for (int ni = 0; ni < 2; ++ni) {
        float p = ((wrd >> (ni*16 + l15)) & 1u)
                    ? __builtin_amdgcn_exp2f(acc[mh][nh][mi][ni][j] * SCL) : 0.f;
        srow[(size_t)q*SEQ + kt*256 + nh*128 + wn*32 + ni*16 + l15] = f2bf(p);
        rsum[mh][mi][j] += p;
      }
    }
  }
  // reduce this wave's k-slice partial over l15 (lane bits 0-3 only)
#pragma unroll
  for (int off = 8; off >= 1; off >>= 1)
#pragma unroll
    for (int mh = 0; mh < 2; ++mh)
#pragma unroll
      for (int mi = 0; mi < 4; ++mi)
#pragma unroll
        for (int j = 0; j < 4; ++j)
          rsum[mh][mi][j] += __shfl_xor(rsum[mh][mi][j], off);

  float* sm = (float*)smem;                        // [4 wn][256 rows]
  if (l15 == 0) {
#pragma unroll
    for (int mh = 0; mh < 2; ++mh)
#pragma unroll
      for (int mi = 0; mi < 4; ++mi)
#pragma unroll
        for (int j = 0; j < 4; ++j)
          sm[wn*256 + mh*128 + wm*64 + mi*16 + l4*4 + j] = rsum[mh][mi][j];
  }
  __syncthreads();
  if (t < 256) {
    float s4 = (sm[t] + sm[256+t]) + (sm[512+t] + sm[768+t]);  // fixed order
    partial[(size_t)kt*M_TOT + b*SEQ + qt*256 + t] = s4;
  }
}

// ---------------------------------------------------------------------------
// lred: invl[row] = 1 / sum_kt partial[kt][row]. Deterministic. Grid 64.
// ---------------------------------------------------------------------------
__global__ __launch_bounds__(256) void lred(
    const float* __restrict__ partial, float* __restrict__ invl)
{
  int i = blockIdx.x * 256 + threadIdx.x;
  float s = 0.f;
#pragma unroll
  for (int kt = 0; kt < 8; ++kt) s += partial[(size_t)kt*M_TOT + i];
  invl[i] = 1.0f / s;
}

// ---------------------------------------------------------------------------
// pv: out[b,q,d] = invl[b,q] * sum_k P[b,q,k]*Vt[b,d,k]. Grid 192 =
// 8 b x 8 qt x 3 dt (batch per XCD). K-tiles 32.
// ---------------------------------------------------------------------------
__global__ __launch_bounds__(512, 2) void pv(
    const short* __restrict__ P, const short* __restrict__ Vt,
    const float* __restrict__ invl, float* __restrict__ out)
{
  extern __shared__ char smem[];
  const int t = threadIdx.x, lane = t & 63, w = t >> 6;
  const int wm = w >> 2, wn = w & 3, l15 = lane & 15, l4 = lane >> 4;

  const int bid = blockIdx.x;
  const int nb = (bid & 7) * 24 + (bid >> 3);      // 192 % 8 == 0
  const int b = nb / 24;
  const int idx = nb % 24;
  const int qt = idx / 3, dt = idx % 3;

  const short* asrc = P  + ((size_t)b*SEQ + qt*256) * SEQ;
  const short* bsrc = Vt + ((size_t)b*EMB + dt*256) * SEQ;

  GEMM_PRO_BODY(asrc, bsrc, SEQ, SEQ, 32)

#pragma unroll
  for (int mh = 0; mh < 2; ++mh)
#pragma unroll
  for (int nh = 0; nh < 2; ++nh)
#pragma unroll
  for (int mi = 0; mi < 4; ++mi)
#pragma unroll
  for (int j = 0; j < 4; ++j) {
    int q = qt*256 + mh*128 + wm*64 + mi*16 + l4*4 + j;
    float il = invl[b*SEQ + q];
    float* orow = out + ((size_t)b*SEQ + q) * EMB;
#pragma unroll
    for (int ni = 0; ni < 2; ++ni) {
      int d = dt*256 + nh*128 + wn*32 + ni*16 + l15;
      orow[d] = acc[mh][nh][mi][ni][j] * il;
    }
  }
}

// ---------------------------------------------------------------------------
extern "C" void kernel_launch(void* const* d_in, const int* in_sizes, int n_in,
                              void* d_out, int out_size, void* d_ws, size_t ws_size,
                              hipStream_t stream)
{
  (void)in_sizes; (void)n_in; (void)out_size; (void)ws_size;
  const float* x  = (const float*)d_in[0];
  const float* Wv = (const float*)d_in[1];
  const float* Wk = (const float*)d_in[2];
  const float* Wq = (const float*)d_in[3];
  const int* mask = (const int*)d_in[4];
  float* out = (float*)d_out;

  // ws: Qb | Kb | Vt (bf16, 24MiB each) | S/P (bf16, 64MiB) | partial | invl
  // (~136.6 MiB). xb/Wb alias S (dead before energy writes P). Bitmask
  // (4 MiB) lives in d_out -- written by qkv's fused packer, consumed by
  // energy, overwritten by pv.
  short* Qb = (short*)d_ws;
  short* Kb = Qb + (size_t)M_TOT * EMB;
  short* Vt = Kb + (size_t)M_TOT * EMB;
  short* S  = Vt + (size_t)M_TOT * EMB;
  float* partial = (float*)(S + (size_t)NBATCH * SEQ * SEQ);   // 8*M_TOT f32
  float* invl = partial + (size_t)8 * M_TOT;                   // M_TOT f32
  short* xb = S;
  short* Wb = S + (size_t)M_TOT * EMB;
  unsigned int* bits = (unsigned int*)d_out;                   // 4 MiB scratch

  cvt_xw<<<dim3(2048), dim3(256), 0, stream>>>(x, Wq, Wk, Wv, xb, Wb);
  qkv_gemm<<<dim3(2304), dim3(256), 0, stream>>>(xb, Wb, mask, Qb, Kb, Vt, bits);
  energy<<<dim3(512), dim3(512), 131072, stream>>>(Qb, Kb, bits, S, partial);
  lred<<<dim3(64), dim3(256), 0, stream>>>(partial, invl);
  pv<<<dim3(192), dim3(512), 131072, stream>>>(S, Vt, invl, out);
}